// Round 9
// baseline (452.345 us; speedup 1.0000x reference)
//
#include <hip/hip_runtime.h>

#define KC 1024
#define DD 256
#define NROWS 65536
#define BM 128
#define NT 512
#define RESCUE_EPS 0.004f
#define CHUNK 8192

typedef __bf16 bf16x8 __attribute__((ext_vector_type(8)));
typedef float f32x4 __attribute__((ext_vector_type(4)));

__device__ __forceinline__ unsigned short f32_bf16_rne(float f) {
    unsigned int u = __float_as_uint(f);
    u += 0x7fffu + ((u >> 16) & 1u);
    return (unsigned short)(u >> 16);
}
__device__ __forceinline__ float bf16_f32(unsigned short h) {
    return __uint_as_float(((unsigned int)h) << 16);
}
__device__ __forceinline__ bf16x8 pack8(const unsigned short* h) {
    union { unsigned short u[8]; bf16x8 b; } cv;
#pragma unroll
    for (int q = 0; q < 8; ++q) cv.u[q] = h[q];
    return cv.b;
}

// fused: W -> bf16 hi/lo + |e_k|^2
__global__ void wprep(const float* __restrict__ W, unsigned short* __restrict__ wh,
                      unsigned short* __restrict__ wl, float* __restrict__ se) {
    int k = blockIdx.x, lane = threadIdx.x;
    float4 v = reinterpret_cast<const float4*>(W + (size_t)k * DD)[lane];
    float vv[4] = {v.x, v.y, v.z, v.w};
    unsigned short h4[4], l4[4];
    double s = 0.0;
#pragma unroll
    for (int q = 0; q < 4; ++q) {
        h4[q] = f32_bf16_rne(vv[q]);
        l4[q] = f32_bf16_rne(vv[q] - bf16_f32(h4[q]));
        s += (double)vv[q] * vv[q];
    }
    *reinterpret_cast<uint2*>(wh + (size_t)k * DD + lane * 4) = *reinterpret_cast<uint2*>(h4);
    *reinterpret_cast<uint2*>(wl + (size_t)k * DD + lane * 4) = *reinterpret_cast<uint2*>(l4);
    for (int m = 32; m >= 1; m >>= 1) s += __shfl_xor(s, m, 64);
    if (lane == 0) se[k] = (float)s;
}

__global__ __launch_bounds__(NT, 4) void vq_mfma(
    const float* __restrict__ X, const float* __restrict__ Wf,
    const unsigned short* __restrict__ wh, const unsigned short* __restrict__ wl,
    const float* __restrict__ se,
    float* __restrict__ out_q, float* __restrict__ out_idx,
    int* __restrict__ idx_int, float* __restrict__ sx_out,
    int* __restrict__ flags, int* __restrict__ count,
    float* __restrict__ counts, double* __restrict__ loss_acc)
{
    __shared__ __align__(16) unsigned short wt[2][2][32 * 256];  // 64 KB
    __shared__ float sxs[BM];
    __shared__ float ses[KC];
    __shared__ int argidx[BM];
    __shared__ double lred[8];

    const int tid = threadIdx.x;
    const int row0 = blockIdx.x * BM;
    const int w = tid >> 6, lane = tid & 63;
    const int m = lane & 15, g = lane >> 4;

    for (int i = tid; i < KC; i += NT) ses[i] = se[i];

    // A-fragments for row w*16+m, all k (8 ks-groups), hi/lo
    bf16x8 ahr[8], alr[8];
    {
        const float* xr = X + (size_t)(row0 + w * 16 + m) * DD;
        double ss = 0.0;
#pragma unroll
        for (int ks = 0; ks < 8; ++ks) {
            float4 a = *reinterpret_cast<const float4*>(xr + ks * 32 + g * 8);
            float4 b = *reinterpret_cast<const float4*>(xr + ks * 32 + g * 8 + 4);
            float v[8] = {a.x, a.y, a.z, a.w, b.x, b.y, b.z, b.w};
            unsigned short h8[8], l8[8];
#pragma unroll
            for (int q = 0; q < 8; ++q) {
                h8[q] = f32_bf16_rne(v[q]);
                l8[q] = f32_bf16_rne(v[q] - bf16_f32(h8[q]));
                ss += (double)v[q] * v[q];
            }
            ahr[ks] = pack8(h8);
            alr[ks] = pack8(l8);
        }
        ss += __shfl_xor(ss, 16, 64);
        ss += __shfl_xor(ss, 32, 64);
        if (g == 0) sxs[w * 16 + m] = (float)ss;
    }

    uint4 sreg[4];
    auto stage_load = [&](int ct) {
        int base = ct * 32;
#pragma unroll
        for (int p = 0; p < 2; ++p) {
            int idx = p * NT + tid, code = idx >> 5, c = idx & 31;
            size_t go = ((size_t)(base + code)) * DD + c * 8;
            sreg[p]     = *reinterpret_cast<const uint4*>(wh + go);
            sreg[2 + p] = *reinterpret_cast<const uint4*>(wl + go);
        }
    };
    auto stage_write = [&](int buf) {
#pragma unroll
        for (int p = 0; p < 2; ++p) {
            int idx = p * NT + tid, code = idx >> 5, c = idx & 31;
            int cp = c ^ (code & 7);
            *reinterpret_cast<uint4*>(&wt[buf][0][code * 256 + cp * 8]) = sreg[p];
            *reinterpret_cast<uint4*>(&wt[buf][1][code * 256 + cp * 8]) = sreg[2 + p];
        }
    };

    stage_load(0); stage_write(0);
    __syncthreads();

    float b1[2], b2[2];
    int i1[2];
    float bb1[4] = {3.4e38f, 3.4e38f, 3.4e38f, 3.4e38f};
    float bb2[4] = {3.4e38f, 3.4e38f, 3.4e38f, 3.4e38f};
    int bi1[4] = {0, 0, 0, 0};
    // per-j running best over codes; store per j (4 C-rows per lane)
    float rb1[2][4], rb2[2][4];
    int ri1[2][4];
#pragma unroll
    for (int cs = 0; cs < 2; ++cs)
#pragma unroll
        for (int j = 0; j < 4; ++j) { rb1[cs][j] = 3.4e38f; rb2[cs][j] = 3.4e38f; ri1[cs][j] = 0; }
    (void)b1; (void)b2; (void)i1; (void)bb1; (void)bb2; (void)bi1;

    for (int ct = 0; ct < 32; ++ct) {
        const int buf = ct & 1;
        if (ct < 31) stage_load(ct + 1);

        const unsigned short* wth0 = &wt[buf][0][(0 * 16 + m) * 256];
        const unsigned short* wtl0 = &wt[buf][1][(0 * 16 + m) * 256];
        const unsigned short* wth1 = &wt[buf][0][(1 * 16 + m) * 256];
        const unsigned short* wtl1 = &wt[buf][1][(1 * 16 + m) * 256];
        f32x4 acc0 = {0.f, 0.f, 0.f, 0.f}, acc1 = {0.f, 0.f, 0.f, 0.f};
#pragma unroll
        for (int ks = 0; ks < 8; ++ks) {
            int cp = ((ks * 4 + g) ^ (m & 7)) * 8;
            bf16x8 bh0 = *reinterpret_cast<const bf16x8*>(wth0 + cp);
            bf16x8 bl0 = *reinterpret_cast<const bf16x8*>(wtl0 + cp);
            bf16x8 bh1 = *reinterpret_cast<const bf16x8*>(wth1 + cp);
            bf16x8 bl1 = *reinterpret_cast<const bf16x8*>(wtl1 + cp);
            acc0 = __builtin_amdgcn_mfma_f32_16x16x32_bf16(ahr[ks], bh0, acc0, 0, 0, 0);
            acc1 = __builtin_amdgcn_mfma_f32_16x16x32_bf16(ahr[ks], bh1, acc1, 0, 0, 0);
            acc0 = __builtin_amdgcn_mfma_f32_16x16x32_bf16(alr[ks], bh0, acc0, 0, 0, 0);
            acc1 = __builtin_amdgcn_mfma_f32_16x16x32_bf16(alr[ks], bh1, acc1, 0, 0, 0);
            acc0 = __builtin_amdgcn_mfma_f32_16x16x32_bf16(ahr[ks], bl0, acc0, 0, 0, 0);
            acc1 = __builtin_amdgcn_mfma_f32_16x16x32_bf16(ahr[ks], bl1, acc1, 0, 0, 0);
        }
#pragma unroll
        for (int cs = 0; cs < 2; ++cs) {
            const int code = ct * 32 + cs * 16 + m;
            const float sec = ses[code];
            f32x4 A = cs ? acc1 : acc0;
#pragma unroll
            for (int j = 0; j < 4; ++j) {
                float s = __fsub_rn(__fadd_rn(sxs[w * 16 + g * 4 + j], sec),
                                    __fmul_rn(2.0f, A[j]));
                if (s < rb1[cs][j]) { rb2[cs][j] = rb1[cs][j]; rb1[cs][j] = s; ri1[cs][j] = code; }
                else if (s < rb2[cs][j]) { rb2[cs][j] = s; }
            }
        }
        if (ct < 31) stage_write(buf ^ 1);
        __syncthreads();
    }

    // merge cs=0/1 then reduce over the 16 m-lanes
#pragma unroll
    for (int j = 0; j < 4; ++j) {
        float v1 = rb1[0][j], v2 = rb2[0][j];
        int ix = ri1[0][j];
        {
            float ov1 = rb1[1][j], ov2 = rb2[1][j];
            int oi = ri1[1][j];
            float nv2 = fminf(fminf(v2, ov2), fmaxf(v1, ov1));
            if (ov1 < v1 || (ov1 == v1 && oi < ix)) { v1 = ov1; ix = oi; }
            v2 = nv2;
        }
        for (int mm = 1; mm < 16; mm <<= 1) {
            float ov1 = __shfl_xor(v1, mm, 64);
            int oi = __shfl_xor(ix, mm, 64);
            float ov2 = __shfl_xor(v2, mm, 64);
            float nv2 = fminf(fminf(v2, ov2), fmaxf(v1, ov1));
            if (ov1 < v1 || (ov1 == v1 && oi < ix)) { v1 = ov1; ix = oi; }
            v2 = nv2;
        }
        if (m == 0) {
            int rl = w * 16 + g * 4 + j;
            argidx[rl] = ix;
            if (v2 - v1 < RESCUE_EPS) {
                int p = atomicAdd(count, 1);
                flags[p] = row0 + rl;
            }
        }
    }
    __syncthreads();

    if (tid < BM) {
        int row = row0 + tid;
        int k = argidx[tid];
        idx_int[row] = k;
        out_idx[row] = (float)k;
        sx_out[row] = sxs[tid];
        atomicAdd(&counts[k], 1.0f);
    }

    // coalesced epilogue: wave w owns rows w*16..w*16+15; 64 lanes x float4 = full row
    {
        double lacc = 0.0;
        for (int i = 0; i < 16; ++i) {
            const int rl = w * 16 + i;
            const int row = row0 + rl;
            const int k = argidx[rl];
            float4 q = reinterpret_cast<const float4*>(Wf + (size_t)k * DD)[lane];
            float4 x = reinterpret_cast<const float4*>(X + (size_t)row * DD)[lane];
            float4 df, o4;
            df.x = q.x - x.x; df.y = q.y - x.y; df.z = q.z - x.z; df.w = q.w - x.w;
            o4.x = x.x + df.x; o4.y = x.y + df.y; o4.z = x.z + df.z; o4.w = x.w + df.w;
            reinterpret_cast<float4*>(out_q + (size_t)row * DD)[lane] = o4;
            lacc += (double)df.x * df.x + (double)df.y * df.y +
                    (double)df.z * df.z + (double)df.w * df.w;
        }
        for (int mm = 32; mm >= 1; mm >>= 1) lacc += __shfl_xor(lacc, mm, 64);
        if (lane == 0) lred[w] = lacc;
    }
    __syncthreads();
    if (tid == 0) {
        double t = 0.0;
        for (int i = 0; i < 8; ++i) t += lred[i];
        atomicAdd(loss_acc, t);
    }
}

__global__ __launch_bounds__(256) void rescue(
    const float* __restrict__ X, const float* __restrict__ Wf,
    const float* __restrict__ se, const float* __restrict__ sx,
    const int* __restrict__ flags, const int* __restrict__ count,
    int* __restrict__ idx_int, float* __restrict__ out_idx,
    float* __restrict__ out_q, float* __restrict__ counts,
    double* __restrict__ loss_acc)
{
    __shared__ __align__(16) float xs[DD];
    __shared__ float rv[256];
    __shared__ int ri[256];
    __shared__ int s_ko, s_kn;
    __shared__ double dred[4];
    const int t = threadIdx.x;
    const int n = count[0];
    for (int i = blockIdx.x; i < n; i += gridDim.x) {
        const int row = flags[i];
        if (t < 64) {
            float4 v = reinterpret_cast<const float4*>(X + (size_t)row * DD)[t];
            *reinterpret_cast<float4*>(&xs[t * 4]) = v;
        }
        __syncthreads();
        const float sxr = sx[row];
        float best = 3.4e38f;
        int bi = 0;
#pragma unroll
        for (int cc = 0; cc < 4; ++cc) {
            int c = cc * 256 + t;
            const float* wr = Wf + (size_t)c * DD;
            float acc = 0.0f;
            for (int d = 0; d < DD; ++d) acc = fmaf(xs[d], wr[d], acc);
            float s = __fsub_rn(__fadd_rn(sxr, se[c]), __fmul_rn(2.0f, acc));
            if (s < best || (s == best && c < bi)) { best = s; bi = c; }
        }
        rv[t] = best; ri[t] = bi;
        __syncthreads();
        for (int sft = 128; sft >= 1; sft >>= 1) {
            if (t < sft) {
                float ov = rv[t + sft];
                int oi = ri[t + sft];
                if (ov < rv[t] || (ov == rv[t] && oi < ri[t])) { rv[t] = ov; ri[t] = oi; }
            }
            __syncthreads();
        }
        if (t == 0) {
            int kn = ri[0], ko = idx_int[row];
            s_ko = ko; s_kn = kn;
            if (kn != ko) {
                idx_int[row] = kn;
                out_idx[row] = (float)kn;
                atomicAdd(&counts[ko], -1.0f);
                atomicAdd(&counts[kn], 1.0f);
            }
        }
        __syncthreads();
        const int ko = s_ko, kn = s_kn;
        if (kn != ko) {
            float x = xs[t];
            float qo = Wf[(size_t)ko * DD + t];
            float qn = Wf[(size_t)kn * DD + t];
            float dfn = qn - x, dfo = qo - x;
            out_q[(size_t)row * DD + t] = x + dfn;
            double dl = (double)dfn * dfn - (double)dfo * dfo;
            for (int mm = 32; mm >= 1; mm >>= 1) dl += __shfl_xor(dl, mm, 64);
            if ((t & 63) == 0) dred[t >> 6] = dl;
            __syncthreads();
            if (t == 0) atomicAdd(loss_acc, dred[0] + dred[1] + dred[2] + dred[3]);
        }
        __syncthreads();
    }
}

__global__ __launch_bounds__(256) void emb_reduce(
    const float* __restrict__ X, const int* __restrict__ idx_int,
    float* __restrict__ emb)
{
    __shared__ int list[CHUNK];
    __shared__ int cnt;
    const int k = blockIdx.x;
    const int t = threadIdx.x;
    float acc = 0.0f;
    for (int base = 0; base < NROWS; base += CHUNK) {
        if (t == 0) cnt = 0;
        __syncthreads();
        for (int i = t; i < CHUNK; i += 256) {
            if (idx_int[base + i] == k) {
                int p = atomicAdd(&cnt, 1);
                list[p] = base + i;
            }
        }
        __syncthreads();
        const int n = cnt;
        for (int i = 0; i < n; ++i)
            acc += X[(size_t)list[i] * DD + t];
        __syncthreads();
    }
    emb[(size_t)k * DD + t] = acc;
}

__global__ void fin1(const float* __restrict__ ema_cs, float* __restrict__ ncs_buf,
                     const double* __restrict__ loss_acc, float* __restrict__ out_loss,
                     float* __restrict__ n_out)
{
    __shared__ float red[1024];
    int t = threadIdx.x;
    const float OM = (float)(1.0 - 0.99);
    float ncs = __fadd_rn(__fmul_rn(0.99f, ema_cs[t]), __fmul_rn(OM, ncs_buf[t]));
    ncs_buf[t] = ncs;
    red[t] = ncs;
    __syncthreads();
    for (int s = 512; s >= 1; s >>= 1) {
        if (t < s) red[t] += red[t + s];
        __syncthreads();
    }
    if (t == 0) {
        n_out[0] = red[0];
        float el = (float)(loss_acc[0] / 16777216.0);
        out_loss[0] = __fadd_rn(el, __fmul_rn(0.25f, el));
    }
}

__global__ __launch_bounds__(256) void fin2(const float* __restrict__ ema_avg,
                                            float* __restrict__ avg_buf,
                                            const float* __restrict__ ncs,
                                            const float* __restrict__ n_ptr,
                                            float* __restrict__ out_w)
{
    int k = blockIdx.x, d = threadIdx.x;
    const float OM = (float)(1.0 - 0.99);
    const float KEPS = (float)(1024.0 * 1e-5);
    size_t i = (size_t)k * DD + d;
    float avg = __fadd_rn(__fmul_rn(0.99f, ema_avg[i]), __fmul_rn(OM, avg_buf[i]));
    float n = n_ptr[0];
    float cs = __fmul_rn(__fdiv_rn(__fadd_rn(ncs[k], 1e-5f), __fadd_rn(n, KEPS)), n);
    avg_buf[i] = avg;
    out_w[i] = __fdiv_rn(avg, cs);
}

extern "C" void kernel_launch(void* const* d_in, const int* in_sizes, int n_in,
                              void* d_out, int out_size, void* d_ws, size_t ws_size,
                              hipStream_t stream) {
    const float* X = (const float*)d_in[0];
    const float* W = (const float*)d_in[1];
    const float* ema_cs = (const float*)d_in[2];
    const float* ema_avg = (const float*)d_in[3];

    float* out = (float*)d_out;
    float* out_q    = out;
    float* out_loss = out + 16777216;
    float* out_idx  = out + 16777217;
    float* out_w    = out + 16842753;
    float* out_ncs  = out + 17104897;
    float* out_avg  = out + 17105921;

    char* ws = (char*)d_ws;
    float* se      = (float*)(ws + 0);
    float* n_ptr   = (float*)(ws + 4096);
    double* loss   = (double*)(ws + 4112);
    int*   count   = (int*)(ws + 4128);
    unsigned short* wh = (unsigned short*)(ws + 8192);
    unsigned short* wl = (unsigned short*)(ws + 8192 + 524288);
    float* sx      = (float*)(ws + 1056768);
    int*   idx_int = (int*)(ws + 1318912);
    int*   flags   = (int*)(ws + 1581056);

    hipMemsetAsync(out_ncs, 0, 1024 * sizeof(float), stream);
    hipMemsetAsync(loss, 0, sizeof(double), stream);
    hipMemsetAsync(count, 0, sizeof(int), stream);

    wprep<<<KC, 64, 0, stream>>>(W, wh, wl, se);
    vq_mfma<<<NROWS / BM, NT, 0, stream>>>(X, W, wh, wl, se, out_q, out_idx,
                                           idx_int, sx, flags, count,
                                           out_ncs, loss);
    rescue<<<256, 256, 0, stream>>>(X, W, se, sx, flags, count, idx_int, out_idx,
                                    out_q, out_ncs, loss);
    emb_reduce<<<KC, 256, 0, stream>>>(X, idx_int, out_avg);
    fin1<<<1, 1024, 0, stream>>>(ema_cs, out_ncs, loss, out_loss, n_ptr);
    fin2<<<KC, 256, 0, stream>>>(ema_avg, out_avg, out_ncs, n_ptr, out_w);
}

// Round 10
// 331.796 us; speedup vs baseline: 1.3633x; 1.3633x over previous
//
#include <hip/hip_runtime.h>

#define KC 1024
#define DD 256
#define NROWS 65536
#define BM 256
#define NT 512
#define RESCUE_EPS 0.004f
#define CHUNK 8192

typedef __bf16 bf16x8 __attribute__((ext_vector_type(8)));
typedef float f32x4 __attribute__((ext_vector_type(4)));

__device__ __forceinline__ unsigned short f32_bf16_rne(float f) {
    unsigned int u = __float_as_uint(f);
    u += 0x7fffu + ((u >> 16) & 1u);
    return (unsigned short)(u >> 16);
}
__device__ __forceinline__ float bf16_f32(unsigned short h) {
    return __uint_as_float(((unsigned int)h) << 16);
}
__device__ __forceinline__ bf16x8 pack8(const unsigned short* h) {
    union { unsigned short u[8]; bf16x8 b; } cv;
#pragma unroll
    for (int q = 0; q < 8; ++q) cv.u[q] = h[q];
    return cv.b;
}

__global__ void wprep(const float* __restrict__ W, unsigned short* __restrict__ wh,
                      unsigned short* __restrict__ wl, float* __restrict__ se) {
    int k = blockIdx.x, lane = threadIdx.x;
    float4 v = reinterpret_cast<const float4*>(W + (size_t)k * DD)[lane];
    float vv[4] = {v.x, v.y, v.z, v.w};
    unsigned short h4[4], l4[4];
    double s = 0.0;
#pragma unroll
    for (int q = 0; q < 4; ++q) {
        h4[q] = f32_bf16_rne(vv[q]);
        l4[q] = f32_bf16_rne(vv[q] - bf16_f32(h4[q]));
        s += (double)vv[q] * vv[q];
    }
    *reinterpret_cast<uint2*>(wh + (size_t)k * DD + lane * 4) = *reinterpret_cast<uint2*>(h4);
    *reinterpret_cast<uint2*>(wl + (size_t)k * DD + lane * 4) = *reinterpret_cast<uint2*>(l4);
    for (int m = 32; m >= 1; m >>= 1) s += __shfl_xor(s, m, 64);
    if (lane == 0) se[k] = (float)s;
}

__global__ __launch_bounds__(NT, 2) void vq_mfma(
    const float* __restrict__ X, const float* __restrict__ Wf,
    const unsigned short* __restrict__ wh, const unsigned short* __restrict__ wl,
    const float* __restrict__ se,
    float* __restrict__ out_q, float* __restrict__ out_idx,
    int* __restrict__ idx_int, float* __restrict__ sx_out,
    int* __restrict__ flags, int* __restrict__ count,
    float* __restrict__ counts, double* __restrict__ loss_acc)
{
    __shared__ __align__(16) unsigned short wt[2][2][64 * 256];  // 128 KB
    __shared__ float sxs[BM];
    __shared__ float ses[KC];
    __shared__ int argidx[BM];
    __shared__ double lred[8];

    const int tid = threadIdx.x;
    const int row0 = blockIdx.x * BM;
    const int w = tid >> 6, lane = tid & 63;
    const int m = lane & 15, g = lane >> 4;

    for (int i = tid; i < KC; i += NT) ses[i] = se[i];

    bf16x8 ahr[2][8], alr[2][8];
#pragma unroll
    for (int rt = 0; rt < 2; ++rt) {
        const float* xr = X + (size_t)(row0 + w * 32 + rt * 16 + m) * DD;
        double ss = 0.0;
#pragma unroll
        for (int ks = 0; ks < 8; ++ks) {
            float4 a = *reinterpret_cast<const float4*>(xr + ks * 32 + g * 8);
            float4 b = *reinterpret_cast<const float4*>(xr + ks * 32 + g * 8 + 4);
            float v[8] = {a.x, a.y, a.z, a.w, b.x, b.y, b.z, b.w};
            unsigned short h8[8], l8[8];
#pragma unroll
            for (int q = 0; q < 8; ++q) {
                h8[q] = f32_bf16_rne(v[q]);
                l8[q] = f32_bf16_rne(v[q] - bf16_f32(h8[q]));
                ss += (double)v[q] * v[q];
            }
            ahr[rt][ks] = pack8(h8);
            alr[rt][ks] = pack8(l8);
        }
        ss += __shfl_xor(ss, 16, 64);
        ss += __shfl_xor(ss, 32, 64);
        if (g == 0) sxs[w * 32 + rt * 16 + m] = (float)ss;
    }

    uint4 sreg[8];
    auto stage_load = [&](int ct) {
        int base = ct * 64;
#pragma unroll
        for (int p = 0; p < 4; ++p) {
            int idx = p * NT + tid, code = idx >> 5, c = idx & 31;
            size_t go = ((size_t)(base + code)) * DD + c * 8;
            sreg[p]     = *reinterpret_cast<const uint4*>(wh + go);
            sreg[4 + p] = *reinterpret_cast<const uint4*>(wl + go);
        }
    };
    auto stage_write = [&](int buf) {
#pragma unroll
        for (int p = 0; p < 4; ++p) {
            int idx = p * NT + tid, code = idx >> 5, c = idx & 31;
            int cp = c ^ (code & 7);
            *reinterpret_cast<uint4*>(&wt[buf][0][code * 256 + cp * 8]) = sreg[p];
            *reinterpret_cast<uint4*>(&wt[buf][1][code * 256 + cp * 8]) = sreg[4 + p];
        }
    };

    stage_load(0); stage_write(0);
    __syncthreads();

    float b1[2][4], b2[2][4];
    int i1[2][4];
#pragma unroll
    for (int rt = 0; rt < 2; ++rt)
#pragma unroll
        for (int j = 0; j < 4; ++j) { b1[rt][j] = 3.4e38f; b2[rt][j] = 3.4e38f; i1[rt][j] = 0; }

    for (int ct = 0; ct < 16; ++ct) {
        const int buf = ct & 1;
        if (ct < 15) stage_load(ct + 1);
#pragma unroll
        for (int csp = 0; csp < 2; ++csp) {
            const unsigned short* wth0 = &wt[buf][0][((csp * 2 + 0) * 16 + m) * 256];
            const unsigned short* wtl0 = &wt[buf][1][((csp * 2 + 0) * 16 + m) * 256];
            const unsigned short* wth1 = &wt[buf][0][((csp * 2 + 1) * 16 + m) * 256];
            const unsigned short* wtl1 = &wt[buf][1][((csp * 2 + 1) * 16 + m) * 256];
            f32x4 a00 = {0.f, 0.f, 0.f, 0.f}, a01 = {0.f, 0.f, 0.f, 0.f};
            f32x4 a10 = {0.f, 0.f, 0.f, 0.f}, a11 = {0.f, 0.f, 0.f, 0.f};
#pragma unroll
            for (int ks = 0; ks < 8; ++ks) {
                int cp = ((ks * 4 + g) ^ (m & 7)) * 8;
                bf16x8 bh0 = *reinterpret_cast<const bf16x8*>(wth0 + cp);
                bf16x8 bl0 = *reinterpret_cast<const bf16x8*>(wtl0 + cp);
                bf16x8 bh1 = *reinterpret_cast<const bf16x8*>(wth1 + cp);
                bf16x8 bl1 = *reinterpret_cast<const bf16x8*>(wtl1 + cp);
                a00 = __builtin_amdgcn_mfma_f32_16x16x32_bf16(ahr[0][ks], bh0, a00, 0, 0, 0);
                a10 = __builtin_amdgcn_mfma_f32_16x16x32_bf16(ahr[1][ks], bh0, a10, 0, 0, 0);
                a01 = __builtin_amdgcn_mfma_f32_16x16x32_bf16(ahr[0][ks], bh1, a01, 0, 0, 0);
                a11 = __builtin_amdgcn_mfma_f32_16x16x32_bf16(ahr[1][ks], bh1, a11, 0, 0, 0);
                a00 = __builtin_amdgcn_mfma_f32_16x16x32_bf16(alr[0][ks], bh0, a00, 0, 0, 0);
                a10 = __builtin_amdgcn_mfma_f32_16x16x32_bf16(alr[1][ks], bh0, a10, 0, 0, 0);
                a01 = __builtin_amdgcn_mfma_f32_16x16x32_bf16(alr[0][ks], bh1, a01, 0, 0, 0);
                a11 = __builtin_amdgcn_mfma_f32_16x16x32_bf16(alr[1][ks], bh1, a11, 0, 0, 0);
                a00 = __builtin_amdgcn_mfma_f32_16x16x32_bf16(ahr[0][ks], bl0, a00, 0, 0, 0);
                a10 = __builtin_amdgcn_mfma_f32_16x16x32_bf16(ahr[1][ks], bl0, a10, 0, 0, 0);
                a01 = __builtin_amdgcn_mfma_f32_16x16x32_bf16(ahr[0][ks], bl1, a01, 0, 0, 0);
                a11 = __builtin_amdgcn_mfma_f32_16x16x32_bf16(ahr[1][ks], bl1, a11, 0, 0, 0);
            }
#pragma unroll
            for (int cs2 = 0; cs2 < 2; ++cs2) {
                const int code = ct * 64 + (csp * 2 + cs2) * 16 + m;
                const float sec = ses[code];
#pragma unroll
                for (int rt = 0; rt < 2; ++rt) {
                    f32x4 A = cs2 ? (rt ? a11 : a01) : (rt ? a10 : a00);
#pragma unroll
                    for (int j = 0; j < 4; ++j) {
                        float s = __fsub_rn(__fadd_rn(sxs[w * 32 + rt * 16 + g * 4 + j], sec),
                                            __fmul_rn(2.0f, A[j]));
                        if (s < b1[rt][j]) { b2[rt][j] = b1[rt][j]; b1[rt][j] = s; i1[rt][j] = code; }
                        else if (s < b2[rt][j]) { b2[rt][j] = s; }
                    }
                }
            }
        }
        if (ct < 15) stage_write(buf ^ 1);
        __syncthreads();
    }

#pragma unroll
    for (int rt = 0; rt < 2; ++rt)
#pragma unroll
        for (int j = 0; j < 4; ++j) {
            float v1 = b1[rt][j], v2 = b2[rt][j];
            int ix = i1[rt][j];
            for (int mm = 1; mm < 16; mm <<= 1) {
                float ov1 = __shfl_xor(v1, mm, 64);
                int oi = __shfl_xor(ix, mm, 64);
                float ov2 = __shfl_xor(v2, mm, 64);
                float nv2 = fminf(fminf(v2, ov2), fmaxf(v1, ov1));
                if (ov1 < v1 || (ov1 == v1 && oi < ix)) { v1 = ov1; ix = oi; }
                v2 = nv2;
            }
            if (m == 0) {
                int rl = w * 32 + rt * 16 + g * 4 + j;
                argidx[rl] = ix;
                if (v2 - v1 < RESCUE_EPS) {
                    int p = atomicAdd(count, 1);
                    flags[p] = row0 + rl;
                }
            }
        }
    __syncthreads();

    if (tid < BM) {
        int row = row0 + tid;
        int k = argidx[tid];
        idx_int[row] = k;
        out_idx[row] = (float)k;
        sx_out[row] = sxs[tid];
        atomicAdd(&counts[k], 1.0f);
    }

    // coalesced epilogue: wave w owns rows w*32..w*32+31; 64 lanes x float4 = full row
    {
        double lacc = 0.0;
        for (int i = 0; i < 32; ++i) {
            const int rl = w * 32 + i;
            const int row = row0 + rl;
            const int k = argidx[rl];
            float4 q = reinterpret_cast<const float4*>(Wf + (size_t)k * DD)[lane];
            float4 x = reinterpret_cast<const float4*>(X + (size_t)row * DD)[lane];
            float4 df, o4;
            df.x = q.x - x.x; df.y = q.y - x.y; df.z = q.z - x.z; df.w = q.w - x.w;
            o4.x = x.x + df.x; o4.y = x.y + df.y; o4.z = x.z + df.z; o4.w = x.w + df.w;
            reinterpret_cast<float4*>(out_q + (size_t)row * DD)[lane] = o4;
            lacc += (double)df.x * df.x + (double)df.y * df.y +
                    (double)df.z * df.z + (double)df.w * df.w;
        }
        for (int mm = 32; mm >= 1; mm >>= 1) lacc += __shfl_xor(lacc, mm, 64);
        if (lane == 0) lred[w] = lacc;
    }
    __syncthreads();
    if (tid == 0) {
        double t = 0.0;
        for (int i = 0; i < 8; ++i) t += lred[i];
        atomicAdd(loss_acc, t);
    }
}

__global__ __launch_bounds__(256) void rescue(
    const float* __restrict__ X, const float* __restrict__ Wf,
    const float* __restrict__ se, const float* __restrict__ sx,
    const int* __restrict__ flags, const int* __restrict__ count,
    int* __restrict__ idx_int, float* __restrict__ out_idx,
    float* __restrict__ out_q, float* __restrict__ counts,
    double* __restrict__ loss_acc)
{
    __shared__ __align__(16) float xs[DD];
    __shared__ float rv[256];
    __shared__ int ri[256];
    __shared__ int s_ko, s_kn;
    __shared__ double dred[4];
    const int t = threadIdx.x;
    const int n = count[0];
    for (int i = blockIdx.x; i < n; i += gridDim.x) {
        const int row = flags[i];
        if (t < 64) {
            float4 v = reinterpret_cast<const float4*>(X + (size_t)row * DD)[t];
            *reinterpret_cast<float4*>(&xs[t * 4]) = v;
        }
        __syncthreads();
        const float sxr = sx[row];
        float best = 3.4e38f;
        int bi = 0;
#pragma unroll
        for (int cc = 0; cc < 4; ++cc) {
            int c = cc * 256 + t;
            const float* wr = Wf + (size_t)c * DD;
            float acc = 0.0f;
            for (int d = 0; d < DD; ++d) acc = fmaf(xs[d], wr[d], acc);
            float s = __fsub_rn(__fadd_rn(sxr, se[c]), __fmul_rn(2.0f, acc));
            if (s < best || (s == best && c < bi)) { best = s; bi = c; }
        }
        rv[t] = best; ri[t] = bi;
        __syncthreads();
        for (int sft = 128; sft >= 1; sft >>= 1) {
            if (t < sft) {
                float ov = rv[t + sft];
                int oi = ri[t + sft];
                if (ov < rv[t] || (ov == rv[t] && oi < ri[t])) { rv[t] = ov; ri[t] = oi; }
            }
            __syncthreads();
        }
        if (t == 0) {
            int kn = ri[0], ko = idx_int[row];
            s_ko = ko; s_kn = kn;
            if (kn != ko) {
                idx_int[row] = kn;
                out_idx[row] = (float)kn;
                atomicAdd(&counts[ko], -1.0f);
                atomicAdd(&counts[kn], 1.0f);
            }
        }
        __syncthreads();
        const int ko = s_ko, kn = s_kn;
        if (kn != ko) {
            float x = xs[t];
            float qo = Wf[(size_t)ko * DD + t];
            float qn = Wf[(size_t)kn * DD + t];
            float dfn = qn - x, dfo = qo - x;
            out_q[(size_t)row * DD + t] = x + dfn;
            double dl = (double)dfn * dfn - (double)dfo * dfo;
            for (int mm = 32; mm >= 1; mm >>= 1) dl += __shfl_xor(dl, mm, 64);
            if ((t & 63) == 0) dred[t >> 6] = dl;
            __syncthreads();
            if (t == 0) atomicAdd(loss_acc, dred[0] + dred[1] + dred[2] + dred[3]);
        }
        __syncthreads();
    }
}

__global__ __launch_bounds__(256) void emb_reduce(
    const float* __restrict__ X, const int* __restrict__ idx_int,
    float* __restrict__ emb)
{
    __shared__ int list[CHUNK];
    __shared__ int cnt;
    const int k = blockIdx.x;
    const int t = threadIdx.x;
    float acc = 0.0f;
    for (int base = 0; base < NROWS; base += CHUNK) {
        if (t == 0) cnt = 0;
        __syncthreads();
        for (int i = t; i < CHUNK; i += 256) {
            if (idx_int[base + i] == k) {
                int p = atomicAdd(&cnt, 1);
                list[p] = base + i;
            }
        }
        __syncthreads();
        const int n = cnt;
        for (int i = 0; i < n; ++i)
            acc += X[(size_t)list[i] * DD + t];
        __syncthreads();
    }
    emb[(size_t)k * DD + t] = acc;
}

__global__ void fin1(const float* __restrict__ ema_cs, float* __restrict__ ncs_buf,
                     const double* __restrict__ loss_acc, float* __restrict__ out_loss,
                     float* __restrict__ n_out)
{
    __shared__ float red[1024];
    int t = threadIdx.x;
    const float OM = (float)(1.0 - 0.99);
    float ncs = __fadd_rn(__fmul_rn(0.99f, ema_cs[t]), __fmul_rn(OM, ncs_buf[t]));
    ncs_buf[t] = ncs;
    red[t] = ncs;
    __syncthreads();
    for (int s = 512; s >= 1; s >>= 1) {
        if (t < s) red[t] += red[t + s];
        __syncthreads();
    }
    if (t == 0) {
        n_out[0] = red[0];
        float el = (float)(loss_acc[0] / 16777216.0);
        out_loss[0] = __fadd_rn(el, __fmul_rn(0.25f, el));
    }
}

__global__ __launch_bounds__(256) void fin2(const float* __restrict__ ema_avg,
                                            float* __restrict__ avg_buf,
                                            const float* __restrict__ ncs,
                                            const float* __restrict__ n_ptr,
                                            float* __restrict__ out_w)
{
    int k = blockIdx.x, d = threadIdx.x;
    const float OM = (float)(1.0 - 0.99);
    const float KEPS = (float)(1024.0 * 1e-5);
    size_t i = (size_t)k * DD + d;
    float avg = __fadd_rn(__fmul_rn(0.99f, ema_avg[i]), __fmul_rn(OM, avg_buf[i]));
    float n = n_ptr[0];
    float cs = __fmul_rn(__fdiv_rn(__fadd_rn(ncs[k], 1e-5f), __fadd_rn(n, KEPS)), n);
    avg_buf[i] = avg;
    out_w[i] = __fdiv_rn(avg, cs);
}

extern "C" void kernel_launch(void* const* d_in, const int* in_sizes, int n_in,
                              void* d_out, int out_size, void* d_ws, size_t ws_size,
                              hipStream_t stream) {
    const float* X = (const float*)d_in[0];
    const float* W = (const float*)d_in[1];
    const float* ema_cs = (const float*)d_in[2];
    const float* ema_avg = (const float*)d_in[3];

    float* out = (float*)d_out;
    float* out_q    = out;
    float* out_loss = out + 16777216;
    float* out_idx  = out + 16777217;
    float* out_w    = out + 16842753;
    float* out_ncs  = out + 17104897;
    float* out_avg  = out + 17105921;

    char* ws = (char*)d_ws;
    float* se      = (float*)(ws + 0);
    float* n_ptr   = (float*)(ws + 4096);
    double* loss   = (double*)(ws + 4112);
    int*   count   = (int*)(ws + 4128);
    unsigned short* wh = (unsigned short*)(ws + 8192);
    unsigned short* wl = (unsigned short*)(ws + 8192 + 524288);
    float* sx      = (float*)(ws + 1056768);
    int*   idx_int = (int*)(ws + 1318912);
    int*   flags   = (int*)(ws + 1581056);

    hipMemsetAsync(out_ncs, 0, 1024 * sizeof(float), stream);
    hipMemsetAsync(loss, 0, sizeof(double), stream);
    hipMemsetAsync(count, 0, sizeof(int), stream);

    wprep<<<KC, 64, 0, stream>>>(W, wh, wl, se);
    vq_mfma<<<NROWS / BM, NT, 0, stream>>>(X, W, wh, wl, se, out_q, out_idx,
                                           idx_int, sx, flags, count,
                                           out_ncs, loss);
    rescue<<<256, 256, 0, stream>>>(X, W, se, sx, flags, count, idx_int, out_idx,
                                    out_q, out_ncs, loss);
    emb_reduce<<<KC, 256, 0, stream>>>(X, idx_int, out_avg);
    fin1<<<1, 1024, 0, stream>>>(ema_cs, out_ncs, loss, out_loss, n_ptr);
    fin2<<<KC, 256, 0, stream>>>(ema_avg, out_avg, out_ncs, n_ptr, out_w);
}